// Round 7
// baseline (66.046 us; speedup 1.0000x reference)
//
#include <hip/hip_runtime.h>

#define BATCH 512
#define T 256
#define C 384
#define H 64

typedef __bf16 bf16x8 __attribute__((ext_vector_type(8)));
typedef __bf16 bf16x4 __attribute__((ext_vector_type(4)));
typedef float f32x4 __attribute__((ext_vector_type(4)));

// LDS byte map (96 KB).
// Phase 1 (per kt, barrier-bracketed):
//   XS @0     (32KB): X k-tile [256 t][64 c] bf16, row stride 128B, swz ^((t&7)<<4)
//   WF @32768 (24KB): 24 W B-frags, frag fl at fl*1024 + lane*16 (linear, conflict-free)
// Phase 2 (overwrites phase-1 regions after a barrier):
//   Ks  @0     (32KB): K [256 t][64 h] bf16, swz ^((t&7)<<4)
//   VT  @32768 (32KB): V^T [64 h][256 t] bf16, row stride 512B, swz ^((h&7)<<4)
//   SCR @65536 (32KB): 16 waves x 2KB [16][64] bf16 swz ^((row&7)<<4) (Q xpose, P stage)
#define XS_OFF 0
#define KS_OFF 0
#define WF_OFF 32768
#define VT_OFF 32768
#define SCR_OFF 65536
#define LDS_BYTES 98304

// wT layout: MFMA B-fragments in lane order. frag fi = ((kt*2+ks)*3+m)*4+n,
// 64 lanes x 16B; lane(l15,g) holds W^T[h=n*16+l15][k=kt*64+ks*32+g*8 ..+8].
__global__ void prep_w(const float* __restrict__ Wq, const float* __restrict__ Wk,
                       const float* __restrict__ Wv, __bf16* __restrict__ wT) {
    const int tid = blockIdx.x * 256 + threadIdx.x;   // 9216 threads
    if (tid >= 9216) return;
    const int lane = tid & 63;
    const int f    = tid >> 6;
    const int n    = f & 3;
    const int f2   = f >> 2;
    const int m    = f2 % 3;
    const int kk   = f2 / 3;
    const int l15  = lane & 15;
    const int g    = lane >> 4;
    const int h    = n * 16 + l15;
    const int k0   = kk * 32 + g * 8;
    const float* W = (m == 0) ? Wq : (m == 1) ? Wk : Wv;
    bf16x8 v;
#pragma unroll
    for (int j = 0; j < 8; ++j) v[j] = (__bf16)W[(k0 + j) * H + h];
    reinterpret_cast<bf16x8*>(wT)[tid] = v;
}

template <bool USE_WT>
__global__ __launch_bounds__(1024, 4) void head_fused(
    const float* __restrict__ x, const float* __restrict__ Wq,
    const float* __restrict__ Wk, const float* __restrict__ Wv,
    const __bf16* __restrict__ wT, float* __restrict__ out)
{
    __shared__ __align__(16) unsigned char lds[LDS_BYTES];
    const int tid  = threadIdx.x;
    const int w    = tid >> 6;        // wave 0..15 == q-tile
    const int lane = tid & 63;
    const int l15  = lane & 15;
    const int g    = lane >> 4;
    const int b    = blockIdx.x;
    const float* xb = x + (size_t)b * T * C;
    const float* wm[3] = {Wq, Wk, Wv};
    const bf16x8* wTv = reinterpret_cast<const bf16x8*>(wT);

    f32x4 acc[3][4];
#pragma unroll
    for (int m = 0; m < 3; ++m)
#pragma unroll
        for (int n = 0; n < 4; ++n)
            acc[m][n] = (f32x4){0.f, 0.f, 0.f, 0.f};

    // X staging: thread covers x[row = tid>>2][kt*64 + (tid&3)*16 .. +16)
    const int xrow = tid >> 2;
    const int xc0  = (tid & 3) << 4;
    float4 pxA[4], pxB[4];            // 2-deep prefetch, parity A=even kt, B=odd kt
    bf16x8 pw0, pw1;                  // W frag slots tid, 1024+tid (tid<512)

    auto loadX = [&](float4 (&P)[4], int kt) {
        const float* s_ = xb + xrow * C + kt * 64 + xc0;
#pragma unroll
        for (int q = 0; q < 4; ++q)
            P[q] = *reinterpret_cast<const float4*>(s_ + 4 * q);
    };
    auto stageX = [&](const float4 (&P)[4]) {
        bf16x8 v0, v1;
#pragma unroll
        for (int j = 0; j < 4; ++j) {
            v0[j]     = (__bf16)P[0][j];
            v0[j + 4] = (__bf16)P[1][j];
            v1[j]     = (__bf16)P[2][j];
            v1[j + 4] = (__bf16)P[3][j];
        }
        const int sw_ = (xrow & 7) << 4;
        *reinterpret_cast<bf16x8*>(lds + XS_OFF + xrow * 128 + ((2 * xc0) ^ sw_)) = v0;
        *reinterpret_cast<bf16x8*>(lds + XS_OFF + xrow * 128 + ((2 * xc0 + 16) ^ sw_)) = v1;
    };
    auto loadW = [&](int kt) {
        if (USE_WT) {
            pw0 = wTv[kt * 1536 + tid];
            if (tid < 512) pw1 = wTv[kt * 1536 + 1024 + tid];
        } else {
#pragma unroll
            for (int ri = 0; ri < 2; ++ri) {
                if (ri == 1 && tid >= 512) break;
                const int s  = ri * 1024 + tid;
                const int fl = s >> 6, ls = s & 63;
                const int n = fl & 3, q = fl >> 2, m = q % 3, ks = q / 3;
                const int k0 = kt * 64 + ks * 32 + ((ls >> 4) << 3);
                const int h  = (n << 4) + (ls & 15);
                bf16x8 v;
#pragma unroll
                for (int j = 0; j < 8; ++j) v[j] = (__bf16)wm[m][(k0 + j) * H + h];
                if (ri == 0) pw0 = v; else pw1 = v;
            }
        }
    };
    auto stageW = [&]() {
        *reinterpret_cast<bf16x8*>(lds + WF_OFF + (tid << 4)) = pw0;
        if (tid < 512)
            *reinterpret_cast<bf16x8*>(lds + WF_OFF + ((1024 + tid) << 4)) = pw1;
    };
    auto compute = [&]() {   // kt-independent: XS/WF are rewritten each step
        bf16x8 af[2];
        const int row = (w << 4) + l15;
#pragma unroll
        for (int ks = 0; ks < 2; ++ks)
            af[ks] = *reinterpret_cast<const bf16x8*>(
                lds + XS_OFF + row * 128 + (((ks << 6) + (g << 4)) ^ ((row & 7) << 4)));
#pragma unroll
        for (int ks = 0; ks < 2; ++ks)
#pragma unroll
            for (int m = 0; m < 3; ++m)
#pragma unroll
                for (int n = 0; n < 4; ++n) {
                    const int fl = ((ks * 3 + m) << 2) + n;
                    const bf16x8 bfr = *reinterpret_cast<const bf16x8*>(
                        lds + WF_OFF + (fl << 10) + (lane << 4));
                    acc[m][n] = __builtin_amdgcn_mfma_f32_16x16x32_bf16(af[ks], bfr, acc[m][n], 0, 0, 0);
                }
    };

    loadX(pxA, 0);
    loadX(pxB, 1);
    loadW(0);

#pragma unroll 1
    for (int kt2 = 0; kt2 < 3; ++kt2) {
        const int kt = kt2 * 2;
        // body A (even kt)
        stageX(pxA); stageW();
        if (kt2 < 2) loadX(pxA, kt + 2);
        loadW(kt + 1);
        __syncthreads();
        compute();
        __syncthreads();
        // body B (odd kt)
        stageX(pxB); stageW();
        if (kt2 < 2) { loadX(pxB, kt + 3); loadW(kt + 2); }
        __syncthreads();
        compute();
        __syncthreads();
    }

    // ---------------- epilogue: K->Ks, V^T->VT, Q->bf16 frags ----------------
    const int tb = w << 4;
#pragma unroll
    for (int n = 0; n < 4; ++n) {
        const int hcol = (n << 4) + l15;
        bf16x4 pv;
#pragma unroll
        for (int r = 0; r < 4; ++r) pv[r] = (__bf16)acc[2][n][r];
        const int trow0 = tb + (g << 2);
        *reinterpret_cast<bf16x4*>(lds + VT_OFF + hcol * 512 + ((2 * trow0) ^ ((hcol & 7) << 4))) = pv;
#pragma unroll
        for (int r = 0; r < 4; ++r) {
            const int trow = trow0 + r;
            *reinterpret_cast<__bf16*>(lds + KS_OFF + trow * 128 + ((2 * hcol) ^ ((trow & 7) << 4))) =
                (__bf16)acc[1][n][r];
        }
    }
    unsigned char* scr = lds + SCR_OFF + (w << 11);
#pragma unroll
    for (int n = 0; n < 4; ++n)
#pragma unroll
        for (int r = 0; r < 4; ++r) {
            const int row = (g << 2) + r;
            *reinterpret_cast<__bf16*>(
                scr + row * 128 + ((2 * ((n << 4) + l15)) ^ ((row & 7) << 4))) = (__bf16)acc[0][n][r];
        }
    const bf16x8 qfa = *reinterpret_cast<const bf16x8*>(
        scr + l15 * 128 + (((g << 4) + 0) ^ ((l15 & 7) << 4)));
    const bf16x8 qfb = *reinterpret_cast<const bf16x8*>(
        scr + l15 * 128 + (((g << 4) + 64) ^ ((l15 & 7) << 4)));
    __syncthreads();   // Ks/VT visible; XS/WF retired

    // ---------------- Phase 2: causal attention (no barriers) ----------------
    const float se = 0.051031036307982884f * 1.4426950408889634f;  // 384^-0.5 * log2(e)
    const int mtu  = __builtin_amdgcn_readfirstlane(w);
    const int q0   = mtu << 4;
    const int qrow = q0 + (g << 2);

    f32x4 o[4];
#pragma unroll
    for (int nh = 0; nh < 4; ++nh) o[nh] = (f32x4){0.f, 0.f, 0.f, 0.f};
    float ssum[4] = {0.f, 0.f, 0.f, 0.f};

#pragma unroll
    for (int kc = 0; kc < 4; ++kc) {
        if (kc <= (mtu >> 2)) {     // wave-uniform causal skip
            f32x4 sb[4];
#pragma unroll
            for (int n4 = 0; n4 < 4; ++n4) sb[n4] = (f32x4){0.f, 0.f, 0.f, 0.f};
#pragma unroll
            for (int ks4 = 0; ks4 < 2; ++ks4) {
                const bf16x8 qv = (ks4 == 0) ? qfa : qfb;
#pragma unroll
                for (int n4 = 0; n4 < 4; ++n4) {
                    const int brow = (kc << 6) + (n4 << 4) + l15;
                    const bf16x8 bfr = *reinterpret_cast<const bf16x8*>(
                        lds + KS_OFF + brow * 128 + (((ks4 << 6) + (g << 4)) ^ ((brow & 7) << 4)));
                    sb[n4] = __builtin_amdgcn_mfma_f32_16x16x32_bf16(qv, bfr, sb[n4], 0, 0, 0);
                }
            }
            // p = exp(s*scale); no max-sub (normalization cancels, |s*scale| small). mask, stage.
#pragma unroll
            for (int n4 = 0; n4 < 4; ++n4) {
                const int k = (kc << 6) + (n4 << 4) + l15;
#pragma unroll
                for (int r = 0; r < 4; ++r) {
                    float p = exp2f(sb[n4][r] * se);
                    if (k > qrow + r) p = 0.f;
                    ssum[r] += p;
                    const int prow = (g << 2) + r;
                    *reinterpret_cast<__bf16*>(
                        scr + prow * 128 + ((2 * ((n4 << 4) + l15)) ^ ((prow & 7) << 4))) = (__bf16)p;
                }
            }
#pragma unroll
            for (int ks4 = 0; ks4 < 2; ++ks4) {
                const bf16x8 pf = *reinterpret_cast<const bf16x8*>(
                    scr + l15 * 128 + (((ks4 << 6) + (g << 4)) ^ ((l15 & 7) << 4)));
#pragma unroll
                for (int nh = 0; nh < 4; ++nh) {
                    const int hrow = (nh << 4) + l15;
                    const bf16x8 vb = *reinterpret_cast<const bf16x8*>(
                        lds + VT_OFF + hrow * 512 +
                        (((kc << 7) + (ks4 << 6) + (g << 4)) ^ ((hrow & 7) << 4)));
                    o[nh] = __builtin_amdgcn_mfma_f32_16x16x32_bf16(pf, vb, o[nh], 0, 0, 0);
                }
            }
        }
    }

#pragma unroll
    for (int d = 1; d < 16; d <<= 1)
#pragma unroll
        for (int r = 0; r < 4; ++r)
            ssum[r] += __shfl_xor(ssum[r], d);

    float inv[4];
#pragma unroll
    for (int r = 0; r < 4; ++r) inv[r] = 1.0f / ssum[r];
    float* ob = out + ((size_t)b * T + q0) * H;
#pragma unroll
    for (int nh = 0; nh < 4; ++nh)
#pragma unroll
        for (int r = 0; r < 4; ++r)
            ob[((g << 2) + r) * H + (nh << 4) + l15] = o[nh][r] * inv[r];
}

extern "C" void kernel_launch(void* const* d_in, const int* in_sizes, int n_in,
                              void* d_out, int out_size, void* d_ws, size_t ws_size,
                              hipStream_t stream) {
    (void)in_sizes; (void)n_in; (void)out_size;
    const float* x  = (const float*)d_in[0];
    const float* Wk = (const float*)d_in[1];
    const float* Wq = (const float*)d_in[2];
    const float* Wv = (const float*)d_in[3];
    float* out = (float*)d_out;
    const size_t wt_bytes = (size_t)9216 * 8 * sizeof(__bf16);
    if (ws_size >= wt_bytes) {
        __bf16* wT = (__bf16*)d_ws;
        prep_w<<<dim3(36), dim3(256), 0, stream>>>(Wq, Wk, Wv, wT);
        head_fused<true><<<dim3(BATCH), dim3(1024), 0, stream>>>(x, Wq, Wk, Wv, wT, out);
    } else {
        head_fused<false><<<dim3(BATCH), dim3(1024), 0, stream>>>(x, Wq, Wk, Wv, nullptr, out);
    }
}